// Round 4
// baseline (164.205 us; speedup 1.0000x reference)
//
#include <hip/hip_runtime.h>

// InitMotionParams: out[p,n,i] = sum_j R(p,n)[i,j]*means[p,j] + T(p,n)[i]
// R = cont_6d_to_rmat(sum_k softmax(coefs)[p,k] * motion_rots[k,ts[n],:])
// T = sum_k softmax(coefs)[p,k] * motion_transls[k,ts[n],:]
//
// Structure (round 4): table is wave-uniform -> prologue packs it in d_ws,
// main kernel reads it via uniform s_load (scalar pipe, SGPR operands, no
// LDS). Two threads per gaussian (4 timesteps each) -> 3125 blocks = 12.2
// waves/SIMD available (round 3 was grid-starved at 6.1). Outputs buffered
// in registers and stored once as 3x float4 -> full-line writes (round 3's
// 12B-scattered stores caused 3x write amplification: 112 MB vs 38 MB).
// Softmax: no max-subtraction (inputs ~N(0,1)); 1/sum folded only into the
// translation (Gram-Schmidt is scale-invariant).

constexpr int KK  = 20;
constexpr int BB  = 8;
constexpr int BLK = 256;
constexpr int ROW = 12;   // floats per (n,k) row in ws: 48 B, 16B-aligned

typedef __attribute__((ext_vector_type(2))) float f32x2;

__global__ void gather_tab(const float* __restrict__ motion_rots,    // (K,F,6)
                           const float* __restrict__ motion_transls, // (K,F,3)
                           const int*   __restrict__ ts,             // (B)
                           float* __restrict__ tab,                  // ws
                           int F)
{
    const int tid = threadIdx.x;
    if (tid < BB * KK) {
        const int n = tid / KK, k = tid % KK;
        const int t = ts[n];
        const float* rp = motion_rots    + ((size_t)k * F + t) * 6;
        const float* tp = motion_transls + ((size_t)k * F + t) * 3;
        float* dst = tab + (n * KK + k) * ROW;
        #pragma unroll
        for (int i = 0; i < 6; ++i) dst[i] = rp[i];
        #pragma unroll
        for (int i = 0; i < 3; ++i) dst[6 + i] = tp[i];
        dst[9] = dst[10] = dst[11] = 0.f;
    }
}

__global__ __launch_bounds__(BLK) void motion_fwd(
    const float* __restrict__ motion_coefs, // (G,K)
    const float* __restrict__ means,        // (G,3)
    const float* __restrict__ tab,          // ws: (B,K,ROW) packed, uniform
    float* __restrict__ out,                // (G,B,3)
    int G)
{
    const long long gid = (long long)blockIdx.x * BLK + threadIdx.x;
    const long long p   = gid >> 1;               // gaussian
    const int       h   = (int)(gid & 1);         // timestep half: n = 4h..4h+3
    const long long pc  = p < G ? p : (long long)G - 1;

    // softmax weights, unnormalized (e^c); 1/sum deferred to translation
    float w[KK];
    float s = 0.f;
    const float4* crow = reinterpret_cast<const float4*>(motion_coefs + pc * KK);
    #pragma unroll
    for (int q = 0; q < KK / 4; ++q) {
        const float4 v = crow[q];
        const float e0 = __expf(v.x), e1 = __expf(v.y);
        const float e2 = __expf(v.z), e3 = __expf(v.w);
        w[4*q+0] = e0; w[4*q+1] = e1; w[4*q+2] = e2; w[4*q+3] = e3;
        s += (e0 + e1) + (e2 + e3);
    }
    const float invs = __builtin_amdgcn_rcpf(s);
    const float mx0 = means[pc*3+0], mx1 = means[pc*3+1], mx2 = means[pc*3+2];

    float o[4][3];   // buffered outputs; constant-indexed (unrolled loop)

    #pragma unroll
    for (int nl = 0; nl < 4; ++nl) {
        const int n = h * 4 + nl;
        const float* tn = tab + (size_t)n * KK * ROW;  // uniform address

        f32x2 a01 = {0.f, 0.f}, a23 = {0.f, 0.f};
        f32x2 a45 = {0.f, 0.f}, a67 = {0.f, 0.f};
        float a8 = 0.f;

        #pragma unroll
        for (int k = 0; k < KK; ++k) {
            // uniform loads -> s_load; VALU consumes SGPR operands directly
            const f32x2 t01 = *reinterpret_cast<const f32x2*>(tn + k*ROW + 0);
            const f32x2 t23 = *reinterpret_cast<const f32x2*>(tn + k*ROW + 2);
            const f32x2 t45 = *reinterpret_cast<const f32x2*>(tn + k*ROW + 4);
            const f32x2 t67 = *reinterpret_cast<const f32x2*>(tn + k*ROW + 6);
            const float t8  = tn[k*ROW + 8];
            const float wk  = w[k];
            const f32x2 w2  = {wk, wk};
            a01 += w2 * t01;
            a23 += w2 * t23;
            a45 += w2 * t45;
            a67 += w2 * t67;
            a8   = fmaf(wk, t8, a8);
        }

        const float r0 = a01.x, r1 = a01.y, r2 = a23.x;
        const float r3 = a23.y, r4 = a45.x, r5 = a45.y;

        const float n1 = __builtin_amdgcn_sqrtf(fmaf(r0, r0, fmaf(r1, r1, r2*r2)));
        const float i1 = __builtin_amdgcn_rcpf(fmaxf(n1, 1e-12f));
        const float b10 = r0*i1, b11 = r1*i1, b12 = r2*i1;

        const float d  = fmaf(b10, r3, fmaf(b11, r4, b12*r5));
        const float q0 = fmaf(-d, b10, r3);
        const float q1 = fmaf(-d, b11, r4);
        const float q2 = fmaf(-d, b12, r5);
        const float n2 = __builtin_amdgcn_sqrtf(fmaf(q0, q0, fmaf(q1, q1, q2*q2)));
        const float i2 = __builtin_amdgcn_rcpf(fmaxf(n2, 1e-12f));
        const float b20 = q0*i2, b21 = q1*i2, b22 = q2*i2;

        const float b30 = fmaf(b11, b22, -(b12*b21));
        const float b31 = fmaf(b12, b20, -(b10*b22));
        const float b32 = fmaf(b10, b21, -(b11*b20));

        const float u0 = a67.x * invs;   // transl = acc[6..8]/sum
        const float u1 = a67.y * invs;
        const float u2 = a8    * invs;

        o[nl][0] = fmaf(b10, mx0, fmaf(b20, mx1, fmaf(b30, mx2, u0)));
        o[nl][1] = fmaf(b11, mx0, fmaf(b21, mx1, fmaf(b31, mx2, u1)));
        o[nl][2] = fmaf(b12, mx0, fmaf(b22, mx1, fmaf(b32, mx2, u2)));
    }

    if (p < G) {
        // 12 contiguous floats: out + p*24 + h*12 (16B-aligned: 96p+48h bytes)
        float4* op = reinterpret_cast<float4*>(out + p * (BB*3) + h * 12);
        op[0] = make_float4(o[0][0], o[0][1], o[0][2], o[1][0]);
        op[1] = make_float4(o[1][1], o[1][2], o[2][0], o[2][1]);
        op[2] = make_float4(o[2][2], o[3][0], o[3][1], o[3][2]);
    }
}

extern "C" void kernel_launch(void* const* d_in, const int* in_sizes, int n_in,
                              void* d_out, int out_size, void* d_ws, size_t ws_size,
                              hipStream_t stream) {
    const float* motion_rots    = (const float*)d_in[0];
    const float* motion_transls = (const float*)d_in[1];
    const float* motion_coefs   = (const float*)d_in[2];
    const float* means          = (const float*)d_in[3];
    const int*   ts             = (const int*)d_in[4];
    float* out = (float*)d_out;
    float* tab = (float*)d_ws;   // needs BB*KK*ROW*4 = 7680 B

    const int G = in_sizes[3] / 3;            // means is (G,3)
    const int F = in_sizes[0] / (6 * KK);     // motion_rots is (K,F,6)

    gather_tab<<<1, 192, 0, stream>>>(motion_rots, motion_transls, ts, tab, F);

    const long long nthreads = 2LL * G;       // 2 threads per gaussian
    const int nblk = (int)((nthreads + BLK - 1) / BLK);
    motion_fwd<<<nblk, BLK, 0, stream>>>(motion_coefs, means, tab, out, G);
}

// Round 5
// 35.836 us; speedup vs baseline: 4.5822x; 4.5822x over previous
//
#include <hip/hip_runtime.h>

// InitMotionParams: out[p,n,i] = sum_j R(p,n)[i,j]*means[p,j] + T(p,n)[i]
// R = cont_6d_to_rmat(sum_k softmax(coefs)[p,k] * motion_rots[k,ts[n],:])
// T = sum_k softmax(coefs)[p,k] * motion_transls[k,ts[n],:]
//
// Round-5 structure: the gathered (8,20,9) table is read via uniform s_load
// (scalar pipe). Round-4 lesson: the timestep split must be WAVE-uniform and
// PROVABLY so (readfirstlane), else divergence analysis kills s_load (SGPR
// 96->32, 3x slowdown). Waves 0,1 of each block take timesteps 0-3 for 128
// gaussians; waves 2,3 take timesteps 4-7 of the same gaussians -> 2x grid
// (12.2 waves/SIMD supplied vs round 3's 6.1), half the per-wave serial
// s_load chain, and complementary 48B write-halves merge in L2 (round-4
// evidence: WRITE_SIZE exactly 37.5 MB with this store shape).
// Softmax: no max-subtraction (inputs ~N(0,1)); 1/sum folded only into the
// translation (Gram-Schmidt is scale-invariant in the weights).

constexpr int KK  = 20;
constexpr int BB  = 8;
constexpr int BLK = 256;
constexpr int GPB = 128;  // gaussians per block (2 threads each, wave-level h)
constexpr int ROW = 12;   // floats per (n,k) row in ws: 48 B, 16B-aligned

typedef __attribute__((ext_vector_type(2))) float f32x2;

__global__ void gather_tab(const float* __restrict__ motion_rots,    // (K,F,6)
                           const float* __restrict__ motion_transls, // (K,F,3)
                           const int*   __restrict__ ts,             // (B)
                           float* __restrict__ tab,                  // ws
                           int F)
{
    const int tid = threadIdx.x;
    if (tid < BB * KK) {
        const int n = tid / KK, k = tid % KK;
        const int t = ts[n];
        const float* rp = motion_rots    + ((size_t)k * F + t) * 6;
        const float* tp = motion_transls + ((size_t)k * F + t) * 3;
        float* dst = tab + (n * KK + k) * ROW;
        #pragma unroll
        for (int i = 0; i < 6; ++i) dst[i] = rp[i];
        #pragma unroll
        for (int i = 0; i < 3; ++i) dst[6 + i] = tp[i];
        dst[9] = dst[10] = dst[11] = 0.f;
    }
}

__global__ __launch_bounds__(BLK, 4) void motion_fwd(
    const float* __restrict__ motion_coefs, // (G,K)
    const float* __restrict__ means,        // (G,3)
    const float* __restrict__ tab,          // ws: (B,K,ROW) packed, uniform
    float* __restrict__ out,                // (G,B,3)
    int G)
{
    const int tid = threadIdx.x;
    // wave-uniform timestep half, provably uniform for the compiler:
    const int h = __builtin_amdgcn_readfirstlane(tid >> 7);   // waves 0,1 -> 0; 2,3 -> 1
    const int gloc = ((tid >> 6) & 1) * 64 + (tid & 63);      // 0..127 within block
    const long long p  = (long long)blockIdx.x * GPB + gloc;
    const long long pc = p < G ? p : (long long)G - 1;        // clamp for loads

    // softmax weights, unnormalized (e^c); 1/sum deferred to translation
    float w[KK];
    float s = 0.f;
    const float4* crow = reinterpret_cast<const float4*>(motion_coefs + pc * KK);
    #pragma unroll
    for (int q = 0; q < KK / 4; ++q) {
        const float4 v = crow[q];
        const float e0 = __expf(v.x), e1 = __expf(v.y);
        const float e2 = __expf(v.z), e3 = __expf(v.w);
        w[4*q+0] = e0; w[4*q+1] = e1; w[4*q+2] = e2; w[4*q+3] = e3;
        s += (e0 + e1) + (e2 + e3);
    }
    const float invs = __builtin_amdgcn_rcpf(s);
    const float mx0 = means[pc*3+0], mx1 = means[pc*3+1], mx2 = means[pc*3+2];

    // one timestep: k-reduction (uniform s_load operands) + Gram-Schmidt
    auto do_n = [&](int n, float& O0, float& O1, float& O2) {
        const float* tn = tab + (size_t)n * KK * ROW;  // uniform address

        f32x2 a01 = {0.f, 0.f}, a23 = {0.f, 0.f};
        f32x2 a45 = {0.f, 0.f}, a67 = {0.f, 0.f};
        float a8 = 0.f;

        #pragma unroll
        for (int k = 0; k < KK; ++k) {
            const f32x2 t01 = *reinterpret_cast<const f32x2*>(tn + k*ROW + 0);
            const f32x2 t23 = *reinterpret_cast<const f32x2*>(tn + k*ROW + 2);
            const f32x2 t45 = *reinterpret_cast<const f32x2*>(tn + k*ROW + 4);
            const f32x2 t67 = *reinterpret_cast<const f32x2*>(tn + k*ROW + 6);
            const float t8  = tn[k*ROW + 8];
            const float wk  = w[k];
            const f32x2 w2  = {wk, wk};
            a01 += w2 * t01;
            a23 += w2 * t23;
            a45 += w2 * t45;
            a67 += w2 * t67;
            a8   = fmaf(wk, t8, a8);
        }

        const float r0 = a01.x, r1 = a01.y, r2 = a23.x;
        const float r3 = a23.y, r4 = a45.x, r5 = a45.y;

        const float n1 = __builtin_amdgcn_sqrtf(fmaf(r0, r0, fmaf(r1, r1, r2*r2)));
        const float i1 = __builtin_amdgcn_rcpf(fmaxf(n1, 1e-12f));
        const float b10 = r0*i1, b11 = r1*i1, b12 = r2*i1;

        const float d  = fmaf(b10, r3, fmaf(b11, r4, b12*r5));
        const float q0 = fmaf(-d, b10, r3);
        const float q1 = fmaf(-d, b11, r4);
        const float q2 = fmaf(-d, b12, r5);
        const float n2 = __builtin_amdgcn_sqrtf(fmaf(q0, q0, fmaf(q1, q1, q2*q2)));
        const float i2 = __builtin_amdgcn_rcpf(fmaxf(n2, 1e-12f));
        const float b20 = q0*i2, b21 = q1*i2, b22 = q2*i2;

        const float b30 = fmaf(b11, b22, -(b12*b21));
        const float b31 = fmaf(b12, b20, -(b10*b22));
        const float b32 = fmaf(b10, b21, -(b11*b20));

        const float u0 = a67.x * invs;   // transl = acc[6..8]/sum
        const float u1 = a67.y * invs;
        const float u2 = a8    * invs;

        O0 = fmaf(b10, mx0, fmaf(b20, mx1, fmaf(b30, mx2, u0)));
        O1 = fmaf(b11, mx0, fmaf(b21, mx1, fmaf(b31, mx2, u1)));
        O2 = fmaf(b12, mx0, fmaf(b22, mx1, fmaf(b32, mx2, u2)));
    };

    // four peeled timesteps (compile-time output indexing -> registers)
    float o0,o1,o2,o3,o4,o5,o6,o7,o8,o9,o10,o11;
    do_n(h*4 + 0, o0,  o1,  o2);
    do_n(h*4 + 1, o3,  o4,  o5);
    do_n(h*4 + 2, o6,  o7,  o8);
    do_n(h*4 + 3, o9,  o10, o11);

    if (p < G) {
        // 12 contiguous floats at out + p*24 + h*12 (byte 96p+48h: 16-aligned)
        float4* op = reinterpret_cast<float4*>(out + p * (BB*3) + (size_t)h * 12);
        op[0] = make_float4(o0, o1, o2,  o3);
        op[1] = make_float4(o4, o5, o6,  o7);
        op[2] = make_float4(o8, o9, o10, o11);
    }
}

extern "C" void kernel_launch(void* const* d_in, const int* in_sizes, int n_in,
                              void* d_out, int out_size, void* d_ws, size_t ws_size,
                              hipStream_t stream) {
    const float* motion_rots    = (const float*)d_in[0];
    const float* motion_transls = (const float*)d_in[1];
    const float* motion_coefs   = (const float*)d_in[2];
    const float* means          = (const float*)d_in[3];
    const int*   ts             = (const int*)d_in[4];
    float* out = (float*)d_out;
    float* tab = (float*)d_ws;   // needs BB*KK*ROW*4 = 7680 B

    const int G = in_sizes[3] / 3;            // means is (G,3)
    const int F = in_sizes[0] / (6 * KK);     // motion_rots is (K,F,6)

    gather_tab<<<1, 192, 0, stream>>>(motion_rots, motion_transls, ts, tab, F);

    const int nblk = (G + GPB - 1) / GPB;     // 2 threads per gaussian
    motion_fwd<<<nblk, BLK, 0, stream>>>(motion_coefs, means, tab, out, G);
}

// Round 6
// 33.792 us; speedup vs baseline: 4.8592x; 1.0605x over previous
//
#include <hip/hip_runtime.h>

// InitMotionParams: out[p,n,i] = sum_j R(p,n)[i,j]*means[p,j] + T(p,n)[i]
// R = cont_6d_to_rmat(sum_k softmax(coefs)[p,k] * motion_rots[k,ts[n],:])
// T = sum_k softmax(coefs)[p,k] * motion_transls[k,ts[n],:]
//
// Round-6 structure: gathered (8,20,9) table read via uniform s_load (scalar
// pipe; SGPR operands feed VALU directly). Timestep split is WAVE-level and
// provably uniform (readfirstlane) -- lane-level split kills s_load (round-4:
// SGPR 96->32, 3x slowdown). Now 4 waves/block: wave q handles timesteps
// 2q,2q+1 for the block's 64 gaussians -> 6250 blocks = 24.4 waves/SIMD
// supplied, per-wave serial s_load->FMA chain halved again vs round 5
// (which gave 52->~30 us). Complementary per-wave 24B store quarters of the
// same gaussians merge in L2 (round-4/5 evidence: WRITE_SIZE exactly 37.5MB).
// Softmax: no max-subtraction (inputs ~N(0,1)); 1/sum folded only into the
// translation (Gram-Schmidt is scale-invariant in the weights).

constexpr int KK  = 20;
constexpr int BB  = 8;
constexpr int BLK = 256;
constexpr int GPB = 64;   // gaussians per block (4 waves x 2 timesteps each)
constexpr int ROW = 12;   // floats per (n,k) row in ws: 48 B, 16B-aligned

typedef __attribute__((ext_vector_type(2))) float f32x2;

__global__ void gather_tab(const float* __restrict__ motion_rots,    // (K,F,6)
                           const float* __restrict__ motion_transls, // (K,F,3)
                           const int*   __restrict__ ts,             // (B)
                           float* __restrict__ tab,                  // ws
                           int F)
{
    const int tid = threadIdx.x;
    if (tid < BB * KK) {
        const int n = tid / KK, k = tid % KK;
        const int t = ts[n];
        const float* rp = motion_rots    + ((size_t)k * F + t) * 6;
        const float* tp = motion_transls + ((size_t)k * F + t) * 3;
        float* dst = tab + (n * KK + k) * ROW;
        #pragma unroll
        for (int i = 0; i < 6; ++i) dst[i] = rp[i];
        #pragma unroll
        for (int i = 0; i < 3; ++i) dst[6 + i] = tp[i];
        dst[9] = dst[10] = dst[11] = 0.f;
    }
}

__global__ __launch_bounds__(BLK) void motion_fwd(
    const float* __restrict__ motion_coefs, // (G,K)
    const float* __restrict__ means,        // (G,3)
    const float* __restrict__ tab,          // ws: (B,K,ROW) packed, uniform
    float* __restrict__ out,                // (G,B,3)
    int G)
{
    const int tid = threadIdx.x;
    // wave-uniform timestep quarter, provably uniform for the compiler:
    const int q = __builtin_amdgcn_readfirstlane(tid >> 6);   // wave id 0..3
    const long long p  = (long long)blockIdx.x * GPB + (tid & 63);
    const long long pc = p < G ? p : (long long)G - 1;        // clamp for loads

    // softmax weights, unnormalized (e^c); 1/sum deferred to translation
    float w[KK];
    float s = 0.f;
    const float4* crow = reinterpret_cast<const float4*>(motion_coefs + pc * KK);
    #pragma unroll
    for (int qq = 0; qq < KK / 4; ++qq) {
        const float4 v = crow[qq];
        const float e0 = __expf(v.x), e1 = __expf(v.y);
        const float e2 = __expf(v.z), e3 = __expf(v.w);
        w[4*qq+0] = e0; w[4*qq+1] = e1; w[4*qq+2] = e2; w[4*qq+3] = e3;
        s += (e0 + e1) + (e2 + e3);
    }
    const float invs = __builtin_amdgcn_rcpf(s);
    const float mx0 = means[pc*3+0], mx1 = means[pc*3+1], mx2 = means[pc*3+2];

    // one timestep: k-reduction (uniform s_load operands) + Gram-Schmidt
    auto do_n = [&](int n, float& O0, float& O1, float& O2) {
        const float* tn = tab + (size_t)n * KK * ROW;  // uniform address

        f32x2 a01 = {0.f, 0.f}, a23 = {0.f, 0.f};
        f32x2 a45 = {0.f, 0.f}, a67 = {0.f, 0.f};
        float a8 = 0.f;

        #pragma unroll
        for (int k = 0; k < KK; ++k) {
            const f32x2 t01 = *reinterpret_cast<const f32x2*>(tn + k*ROW + 0);
            const f32x2 t23 = *reinterpret_cast<const f32x2*>(tn + k*ROW + 2);
            const f32x2 t45 = *reinterpret_cast<const f32x2*>(tn + k*ROW + 4);
            const f32x2 t67 = *reinterpret_cast<const f32x2*>(tn + k*ROW + 6);
            const float t8  = tn[k*ROW + 8];
            const float wk  = w[k];
            const f32x2 w2  = {wk, wk};
            a01 += w2 * t01;
            a23 += w2 * t23;
            a45 += w2 * t45;
            a67 += w2 * t67;
            a8   = fmaf(wk, t8, a8);
        }

        const float r0 = a01.x, r1 = a01.y, r2 = a23.x;
        const float r3 = a23.y, r4 = a45.x, r5 = a45.y;

        const float n1 = __builtin_amdgcn_sqrtf(fmaf(r0, r0, fmaf(r1, r1, r2*r2)));
        const float i1 = __builtin_amdgcn_rcpf(fmaxf(n1, 1e-12f));
        const float b10 = r0*i1, b11 = r1*i1, b12 = r2*i1;

        const float d  = fmaf(b10, r3, fmaf(b11, r4, b12*r5));
        const float q0 = fmaf(-d, b10, r3);
        const float q1 = fmaf(-d, b11, r4);
        const float q2 = fmaf(-d, b12, r5);
        const float n2 = __builtin_amdgcn_sqrtf(fmaf(q0, q0, fmaf(q1, q1, q2*q2)));
        const float i2 = __builtin_amdgcn_rcpf(fmaxf(n2, 1e-12f));
        const float b20 = q0*i2, b21 = q1*i2, b22 = q2*i2;

        const float b30 = fmaf(b11, b22, -(b12*b21));
        const float b31 = fmaf(b12, b20, -(b10*b22));
        const float b32 = fmaf(b10, b21, -(b11*b20));

        const float u0 = a67.x * invs;   // transl = acc[6..8]/sum
        const float u1 = a67.y * invs;
        const float u2 = a8    * invs;

        O0 = fmaf(b10, mx0, fmaf(b20, mx1, fmaf(b30, mx2, u0)));
        O1 = fmaf(b11, mx0, fmaf(b21, mx1, fmaf(b31, mx2, u1)));
        O2 = fmaf(b12, mx0, fmaf(b22, mx1, fmaf(b32, mx2, u2)));
    };

    // two peeled timesteps (compile-time output naming -> registers)
    float o0,o1,o2,o3,o4,o5;
    do_n(q*2 + 0, o0, o1, o2);
    do_n(q*2 + 1, o3, o4, o5);

    if (p < G) {
        // 6 contiguous floats at out + p*24 + q*6 (byte 96p+24q: 8-aligned)
        float2* op = reinterpret_cast<float2*>(out + p * (BB*3) + (size_t)q * 6);
        op[0] = make_float2(o0, o1);
        op[1] = make_float2(o2, o3);
        op[2] = make_float2(o4, o5);
    }
}

extern "C" void kernel_launch(void* const* d_in, const int* in_sizes, int n_in,
                              void* d_out, int out_size, void* d_ws, size_t ws_size,
                              hipStream_t stream) {
    const float* motion_rots    = (const float*)d_in[0];
    const float* motion_transls = (const float*)d_in[1];
    const float* motion_coefs   = (const float*)d_in[2];
    const float* means          = (const float*)d_in[3];
    const int*   ts             = (const int*)d_in[4];
    float* out = (float*)d_out;
    float* tab = (float*)d_ws;   // needs BB*KK*ROW*4 = 7680 B

    const int G = in_sizes[3] / 3;            // means is (G,3)
    const int F = in_sizes[0] / (6 * KK);     // motion_rots is (K,F,6)

    gather_tab<<<1, 192, 0, stream>>>(motion_rots, motion_transls, ts, tab, F);

    const int nblk = (G + GPB - 1) / GPB;     // 4 threads per gaussian
    motion_fwd<<<nblk, BLK, 0, stream>>>(motion_coefs, means, tab, out, G);
}